// Round 1
// 469.679 us; speedup vs baseline: 1.0751x; 1.0751x over previous
//
#include <hip/hip_runtime.h>
#include <math.h>

#define BB 2
#define NCAM 6
#define CC 256
#define HH 116
#define WW 200
#define QQ 900
#define DD 256
#define NHD 8
#define HD 32
#define HWSZ (HH*WW)

__device__ __forceinline__ float sigmoidf_(float x){ return 1.0f/(1.0f+expf(-x)); }

// ---------------- ref = sigmoid(q @ ref_w.T + ref_b)  [Q,3] ----------------
__global__ void ref_kernel(const float* __restrict__ qe, const float* __restrict__ ref_w,
                           const float* __restrict__ ref_b, float* __restrict__ ref) {
    int idx = blockIdx.x*256 + threadIdx.x;
    if (idx >= QQ*3) return;
    int q = idx/3, j = idx%3;
    float acc = ref_b[j];
    const float4* qr = (const float4*)(qe + q*DD);
    const float4* wr = (const float4*)(ref_w + j*DD);
    for (int k=0;k<DD/4;k++) {
        float4 a = qr[k], w = wr[k];
        acc += a.x*w.x + a.y*w.y + a.z*w.z + a.w*w.w;
    }
    ref[idx] = sigmoidf_(acc);
}

// ---------------- project ref points to each camera ----------------
__global__ void proj_kernel(const float* __restrict__ l2i, const float* __restrict__ ref,
        float* __restrict__ wxa, float* __restrict__ wya,
        int* __restrict__ x0a, int* __restrict__ y0a,
        int* __restrict__ maskz, int* __restrict__ inimg) {
    int idx = blockIdx.x*256+threadIdx.x;
    if (idx >= BB*NCAM*QQ) return;
    int q = idx % QQ;
    int bn = idx / QQ;   // b*NCAM+n
    float h0 = ref[q*3+0], h1 = ref[q*3+1], h2 = ref[q*3+2];
    const float* m = l2i + bn*16;
    float px = m[0]*h0+m[1]*h1+m[2]*h2+m[3];
    float py = m[4]*h0+m[5]*h1+m[6]*h2+m[7];
    float pz = m[8]*h0+m[9]*h1+m[10]*h2+m[11];
    float denom = fabsf(pz)+1e-5f;
    float sx = px/denom, sy = py/denom;
    float pnx = sx/(float)(WW-1)*2.0f-1.0f;
    float pny = sy/(float)(HH-1)*2.0f-1.0f;
    maskz[idx] = (pz > 1e-5f) ? 1 : 0;
    inimg[idx] = (fmaxf(fabsf(pnx),fabsf(pny)) < 1.0f) ? 1 : 0;
    float ix = (pnx+1.0f)*(WW*0.5f)-0.5f;
    float iy = (pny+1.0f)*(HH*0.5f)-0.5f;
    float x0f = floorf(ix), y0f = floorf(iy);
    wxa[idx] = ix-x0f; wya[idx] = iy-y0f;
    x0a[idx] = (int)x0f; y0a[idx] = (int)y0f;
}

// ---------------- bilinear gather + masked mean over cams + add q ----------------
// Branch-free per-corner handling: clamp addresses (always safe), zero the weight
// of OOB corners. All coords are wave-uniform per (b,q,n), so the only branch left
// is the uniform per-camera validity skip; the 4 loads per camera issue together.
__global__ __launch_bounds__(256) void sample_kernel(const float* __restrict__ feats,
        const float* __restrict__ qe, const float* __restrict__ wxa, const float* __restrict__ wya,
        const int* __restrict__ x0a, const int* __restrict__ y0a,
        const int* __restrict__ maskz, const int* __restrict__ inimg,
        float* __restrict__ xout) {
    int bq = blockIdx.x;
    int b = bq / QQ, q = bq % QQ;
    int c = threadIdx.x;
    float sum = 0.0f;
    int cnt = 0;
    #pragma unroll
    for (int n = 0; n < NCAM; n++) {
        int s = (b*NCAM+n)*QQ + q;          // matched (b,n,q) index
        int sq = b*(NCAM*QQ) + q*NCAM + n;  // reference's reshape-scrambled index
        int v = maskz[s] & inimg[sq];
        if (!v) continue;
        cnt++;
        float wx = wxa[s], wy = wya[s];
        int x0 = x0a[s], y0 = y0a[s];
        int x1 = x0 + 1, y1 = y0 + 1;
        bool x0in = (unsigned)x0 < (unsigned)WW;
        bool x1in = (unsigned)x1 < (unsigned)WW;
        bool y0in = (unsigned)y0 < (unsigned)HH;
        bool y1in = (unsigned)y1 < (unsigned)HH;
        int x0c = x0in ? x0 : 0;
        int x1c = x1in ? x1 : (WW-1);
        int y0c = y0in ? y0 : 0;
        int y1c = y1in ? y1 : (HH-1);
        float w00 = (x0in && y0in) ? (1.f-wx)*(1.f-wy) : 0.f;
        float w10 = (x1in && y0in) ? wx*(1.f-wy) : 0.f;
        float w01 = (x0in && y1in) ? (1.f-wx)*wy : 0.f;
        float w11 = (x1in && y1in) ? wx*wy : 0.f;
        const float* fb = feats + ((size_t)(b*NCAM+n)*CC + c)*HWSZ;
        const float* r0 = fb + y0c*WW;
        const float* r1 = fb + y1c*WW;
        sum += w00*r0[x0c] + w10*r0[x1c] + w01*r1[x0c] + w11*r1[x1c];
    }
    float tgt = sum / (float)(cnt > 0 ? cnt : 1);
    xout[(size_t)bq*DD + c] = qe[q*DD+c] + tgt;
}

// ---------------- tiled SGEMM: C[M,N] = A[M,K] @ Wt[N,K]^T + bias[N] ----------------
// LDS pad 64->68: staging writes As[k][m] had addr = k*64+m, 64 % 32 == 0 ->
// 16 lanes per bank (16-way conflict). With 68 it's <=2-way (free).
// Staging now float4 (1 global load per array per k-tile per thread).
#define TILE 64
#define BKK 16
__global__ __launch_bounds__(256) void sgemm_nt(const float* __restrict__ A,
        const float* __restrict__ Bw, const float* __restrict__ bias,
        float* __restrict__ Cm, int M, int N, int K) {
    __shared__ float As[BKK][TILE+4];
    __shared__ float Bs[BKK][TILE+4];
    int tid = threadIdx.x;
    int m0 = blockIdx.y * TILE, n0 = blockIdx.x * TILE;
    float acc[4][4] = {};
    int tx = tid & 15, ty = tid >> 4;
    int ms = tid >> 2;              // staging row 0..63
    int kq = (tid & 3) * 4;         // staging k seg
    for (int k0 = 0; k0 < K; k0 += BKK) {
        int gm = m0 + ms;
        float4 fa = (gm < M) ? *(const float4*)(A + (size_t)gm * K + k0 + kq)
                             : make_float4(0.f,0.f,0.f,0.f);
        As[kq+0][ms]=fa.x; As[kq+1][ms]=fa.y; As[kq+2][ms]=fa.z; As[kq+3][ms]=fa.w;
        int gn = n0 + ms;
        float4 fb = (gn < N) ? *(const float4*)(Bw + (size_t)gn * K + k0 + kq)
                             : make_float4(0.f,0.f,0.f,0.f);
        Bs[kq+0][ms]=fb.x; Bs[kq+1][ms]=fb.y; Bs[kq+2][ms]=fb.z; Bs[kq+3][ms]=fb.w;
        __syncthreads();
        #pragma unroll
        for (int k = 0; k < BKK; k++) {
            float a[4], bb[4];
            #pragma unroll
            for (int i = 0; i < 4; i++) a[i] = As[k][ty*4+i];
            #pragma unroll
            for (int j = 0; j < 4; j++) bb[j] = Bs[k][tx*4+j];
            #pragma unroll
            for (int i = 0; i < 4; i++)
                #pragma unroll
                for (int j = 0; j < 4; j++)
                    acc[i][j] += a[i] * bb[j];
        }
        __syncthreads();
    }
    for (int i = 0; i < 4; i++) {
        int gm = m0 + ty*4 + i;
        if (gm >= M) continue;
        for (int j = 0; j < 4; j++) {
            int gn = n0 + tx*4 + j;
            if (gn < N) Cm[(size_t)gm * N + gn] = acc[i][j] + bias[gn];
        }
    }
}

// ---------------- flash-style attention, split-K x2 ----------------
// No max-subtraction (scores O(1); softmax shift-invariant), so split-K partials
// combine exactly: attn = (O0+O1)/(l0+l1). 928 blocks -> 3.6 blocks/CU.
// Q tile hoisted to registers (reused across all k-tiles); Q-stage LDS unioned
// into Ps.
#define QTILE 32
#define KTILE 64
#define NQB 29
__global__ __launch_bounds__(256) void attn_flash(const float* __restrict__ qkv,
        float* __restrict__ opA, float* __restrict__ opB,
        float* __restrict__ lpA, float* __restrict__ lpB) {
    __shared__ __align__(16) float Ks[32][68];   // [d][k]
    __shared__ __align__(16) float Vs[64][36];   // [k][d]
    __shared__ __align__(16) float Ps[32][68];   // [q][k]; also Q staging [d][q]
    int blk = blockIdx.x;
    int qb = blk % NQB;
    int h  = (blk / NQB) % NHD;
    int b  = (blk / (NQB*NHD)) % BB;
    int ks = blk / (NQB*NHD*BB);
    int q0 = qb * QTILE;
    int tid = threadIdx.x;
    int tx = tid & 15, ty = tid >> 4;

    // stage Q tile transposed into Ps area: Ps[d][q]
    {
        int q = tid >> 3;            // 0..31
        int dseg = (tid & 7) * 4;
        int gq = q0 + q; if (gq > QQ-1) gq = QQ-1;
        const float4 f = *(const float4*)(qkv + ((size_t)(b*QQ+gq))*768 + h*HD + dseg);
        Ps[dseg+0][q] = f.x; Ps[dseg+1][q] = f.y; Ps[dseg+2][q] = f.z; Ps[dseg+3][q] = f.w;
    }
    __syncthreads();
    float q0r[32], q1r[32];
    #pragma unroll
    for (int d = 0; d < 32; d++) { q0r[d] = Ps[d][ty*2]; q1r[d] = Ps[d][ty*2+1]; }
    __syncthreads();

    float O[2][2] = {};
    float l[2] = {0.f, 0.f};
    const float scale = 0.17677669529663689f; // 1/sqrt(32)
    int kt0 = ks ? 8 : 0;
    int kt1 = ks ? 15 : 8;

    for (int kt = kt0; kt < kt1; kt++) {
        int k0 = kt * KTILE;
        // stage K (transposed) and V tiles
        {
            int k = tid >> 2;            // 0..63
            int dseg = (tid & 3) * 8;
            int gk = k0 + k; if (gk > QQ-1) gk = QQ-1;
            const float* kp = qkv + ((size_t)(b*QQ+gk))*768 + 256 + h*HD + dseg;
            float4 f0 = *(const float4*)(kp);
            float4 f1 = *(const float4*)(kp+4);
            Ks[dseg+0][k]=f0.x; Ks[dseg+1][k]=f0.y; Ks[dseg+2][k]=f0.z; Ks[dseg+3][k]=f0.w;
            Ks[dseg+4][k]=f1.x; Ks[dseg+5][k]=f1.y; Ks[dseg+6][k]=f1.z; Ks[dseg+7][k]=f1.w;
            const float* vp = qkv + ((size_t)(b*QQ+gk))*768 + 512 + h*HD + dseg;
            *(float4*)(&Vs[k][dseg])   = *(const float4*)(vp);
            *(float4*)(&Vs[k][dseg+4]) = *(const float4*)(vp+4);
        }
        __syncthreads();

        // scores: 2q x 4k register fragment; Q from registers, only K from LDS
        float acc[2][4] = {};
        #pragma unroll
        for (int d = 0; d < 32; d++) {
            float4 bk = *(const float4*)(&Ks[d][tx*4]);
            float a0 = q0r[d], a1 = q1r[d];
            acc[0][0] += a0*bk.x; acc[0][1] += a0*bk.y; acc[0][2] += a0*bk.z; acc[0][3] += a0*bk.w;
            acc[1][0] += a1*bk.x; acc[1][1] += a1*bk.y; acc[1][2] += a1*bk.z; acc[1][3] += a1*bk.w;
        }
        // exp + tail mask + row-sum across tx
        #pragma unroll
        for (int i = 0; i < 2; i++) {
            float e[4];
            float rs = 0.f;
            #pragma unroll
            for (int j = 0; j < 4; j++) {
                int gk = k0 + tx*4 + j;
                float v = (gk < QQ) ? __expf(acc[i][j]*scale) : 0.f;
                e[j] = v; rs += v;
            }
            #pragma unroll
            for (int m = 1; m < 16; m <<= 1) rs += __shfl_xor(rs, m, 16);
            l[i] += rs;
            *(float4*)(&Ps[ty*2+i][tx*4]) = make_float4(e[0],e[1],e[2],e[3]);
        }
        __syncthreads();

        // PV: O[2q][2d] accumulate
        #pragma unroll
        for (int k4 = 0; k4 < 16; k4++) {
            float4 p0 = *(const float4*)(&Ps[ty*2][k4*4]);
            float4 p1 = *(const float4*)(&Ps[ty*2+1][k4*4]);
            float2 v0 = *(const float2*)(&Vs[k4*4+0][tx*2]);
            float2 v1 = *(const float2*)(&Vs[k4*4+1][tx*2]);
            float2 v2 = *(const float2*)(&Vs[k4*4+2][tx*2]);
            float2 v3 = *(const float2*)(&Vs[k4*4+3][tx*2]);
            O[0][0] += p0.x*v0.x + p0.y*v1.x + p0.z*v2.x + p0.w*v3.x;
            O[0][1] += p0.x*v0.y + p0.y*v1.y + p0.z*v2.y + p0.w*v3.y;
            O[1][0] += p1.x*v0.x + p1.y*v1.x + p1.z*v2.x + p1.w*v3.x;
            O[1][1] += p1.x*v0.y + p1.y*v1.y + p1.z*v2.y + p1.w*v3.y;
        }
        __syncthreads();
    }

    float* op = ks ? opB : opA;
    float* lp = ks ? lpB : lpA;
    #pragma unroll
    for (int i = 0; i < 2; i++) {
        int gq = q0 + ty*2 + i;
        if (gq < QQ) {
            float* o = op + (((size_t)(b*NHD+h))*QQ + gq)*HD + tx*2;
            o[0] = O[i][0];
            o[1] = O[i][1];
            if (tx == 0) lp[(b*NHD+h)*QQ + gq] = l[i];
        }
    }
}

// combine split-K partials: attn = (O0+O1)/(l0+l1)
__global__ __launch_bounds__(256) void attn_combine(const float* __restrict__ opA,
        const float* __restrict__ opB, const float* __restrict__ lpA,
        const float* __restrict__ lpB, float* __restrict__ attn_out) {
    int idx = blockIdx.x*256 + threadIdx.x;
    if (idx >= BB*QQ*DD) return;
    int c = idx & 255;
    int bq = idx >> 8;
    int b = bq / QQ, q = bq % QQ;
    int h = c >> 5, d = c & 31;
    size_t base = ((size_t)(b*NHD+h))*QQ + q;
    float o = opA[base*HD + d] + opB[base*HD + d];
    float L = lpA[base] + lpB[base];
    attn_out[idx] = o / L;
}

// ---------------- layernorm + cls/box heads ----------------
__global__ __launch_bounds__(256) void final_kernel(const float* __restrict__ o,
    const float* __restrict__ norm_w, const float* __restrict__ norm_b,
    const float* __restrict__ cls_w, const float* __restrict__ cls_b,
    const float* __restrict__ box_w, const float* __restrict__ box_b,
    float* __restrict__ out) {
    __shared__ float s_xn[DD];
    __shared__ float red[8];
    int bq = blockIdx.x;
    int t = threadIdx.x;
    float val = o[(size_t)bq*DD + t];
    float v1 = val, v2 = val*val;
    for (int off=32; off>0; off>>=1) { v1 += __shfl_down(v1, off); v2 += __shfl_down(v2, off); }
    if ((t & 63) == 0) { red[t>>6] = v1; red[4 + (t>>6)] = v2; }
    __syncthreads();
    float ssum = red[0]+red[1]+red[2]+red[3];
    float ssq  = red[4]+red[5]+red[6]+red[7];
    float mu = ssum / (float)DD;
    float var = ssq / (float)DD - mu*mu;
    float inv = 1.0f / sqrtf(var + 1e-5f);
    s_xn[t] = (val - mu)*inv*norm_w[t] + norm_b[t];
    __syncthreads();
    int j = t >> 5, lane = t & 31;
    const float* wrow = (j < 2) ? (cls_w + j*DD) : (box_w + (j-2)*DD);
    float acc = 0.f;
    for (int k=lane; k<DD; k+=32) acc += s_xn[k]*wrow[k];
    for (int off=16; off>0; off>>=1) acc += __shfl_down(acc, off, 32);
    if (lane == 0) {
        if (j < 2) {
            out[(size_t)bq*2 + j] = acc + cls_b[j];
        } else {
            int jj = j-2;
            float v = acc + box_b[jj];
            if (jj < 3) v = sigmoidf_(v);
            out[BB*QQ*2 + (size_t)bq*6 + jj] = v;
        }
    }
}

extern "C" void kernel_launch(void* const* d_in, const int* in_sizes, int n_in,
                              void* d_out, int out_size, void* d_ws, size_t ws_size,
                              hipStream_t stream) {
    const float* feats = (const float*)d_in[0];
    const float* l2i   = (const float*)d_in[1];
    const float* qe    = (const float*)d_in[2];
    const float* ref_w = (const float*)d_in[3];
    const float* ref_b = (const float*)d_in[4];
    const float* ipw   = (const float*)d_in[5];
    const float* ipb   = (const float*)d_in[6];
    const float* opw   = (const float*)d_in[7];
    const float* opb   = (const float*)d_in[8];
    const float* nw    = (const float*)d_in[9];
    const float* nb    = (const float*)d_in[10];
    const float* clsw  = (const float*)d_in[11];
    const float* clsb  = (const float*)d_in[12];
    const float* boxw  = (const float*)d_in[13];
    const float* boxb  = (const float*)d_in[14];
    float* out = (float*)d_out;
    float* ws = (float*)d_ws;

    float* ref   = ws;                         // 2700
    float* wxa   = ws + 2700;                  // 10800
    float* wya   = wxa + 10800;                // 10800
    int*   x0a   = (int*)(wya + 10800);        // 10800
    int*   y0a   = x0a + 10800;                // 10800
    int*   maskz = y0a + 10800;                // 10800
    int*   inimg = maskz + 10800;              // 10800
    float* x     = (float*)(inimg + 10800);    // 1800*256
    float* qkv   = x + 460800;                 // 1800*768
    float* attn  = qkv + 1382400;              // 1800*256
    float* oproj = attn + 460800;              // 1800*256

    // split-K attention partial overlays (all regions dead during attn phase):
    float* opA = x;            // x dead after qkv GEMM; 460800 = 2*8*900*32 exactly
    float* opB = oproj;        // oproj written only after attn_combine
    float* lpA = wxa;          // proj scratch dead after sample_kernel (needs 14400)
    float* lpB = wxa + 14400;  // next 14400, still within proj scratch

    ref_kernel<<<(QQ*3+255)/256, 256, 0, stream>>>(qe, ref_w, ref_b, ref);
    proj_kernel<<<(BB*NCAM*QQ+255)/256, 256, 0, stream>>>(l2i, ref, wxa, wya, x0a, y0a, maskz, inimg);
    sample_kernel<<<BB*QQ, 256, 0, stream>>>(feats, qe, wxa, wya, x0a, y0a, maskz, inimg, x);
    sgemm_nt<<<dim3(768/TILE, (BB*QQ+TILE-1)/TILE), 256, 0, stream>>>(x, ipw, ipb, qkv, BB*QQ, 768, 256);
    attn_flash<<<BB*NHD*NQB*2, 256, 0, stream>>>(qkv, opA, opB, lpA, lpB);
    attn_combine<<<(BB*QQ*DD+255)/256, 256, 0, stream>>>(opA, opB, lpA, lpB, attn);
    sgemm_nt<<<dim3(256/TILE, (BB*QQ+TILE-1)/TILE), 256, 0, stream>>>(attn, opw, opb, oproj, BB*QQ, 256, 256);
    final_kernel<<<BB*QQ, 256, 0, stream>>>(oproj, nw, nb, clsw, clsb, boxw, boxb, out);
}

// Round 2
// 466.128 us; speedup vs baseline: 1.0833x; 1.0076x over previous
//
#include <hip/hip_runtime.h>
#include <math.h>

#define BB 2
#define NCAM 6
#define CC 256
#define HH 116
#define WW 200
#define QQ 900
#define DD 256
#define NHD 8
#define HD 32
#define HWSZ (HH*WW)

__device__ __forceinline__ float sigmoidf_(float x){ return 1.0f/(1.0f+expf(-x)); }

// ---------------- fused: ref = sigmoid(q @ ref_w.T + b) + project to cameras ----------------
// Each (b,n,q) thread recomputes the 3x256 dot (8.3 MFLOP total - trivial); kills a
// kernel launch + the ref round-trip.
__global__ void proj_kernel(const float* __restrict__ l2i, const float* __restrict__ qe,
        const float* __restrict__ ref_w, const float* __restrict__ ref_b,
        float* __restrict__ wxa, float* __restrict__ wya,
        int* __restrict__ x0a, int* __restrict__ y0a,
        int* __restrict__ maskz, int* __restrict__ inimg) {
    int idx = blockIdx.x*256+threadIdx.x;
    if (idx >= BB*NCAM*QQ) return;
    int q = idx % QQ;
    int bn = idx / QQ;   // b*NCAM+n
    float a0 = ref_b[0], a1 = ref_b[1], a2 = ref_b[2];
    const float4* qr = (const float4*)(qe + (size_t)q*DD);
    const float4* w0 = (const float4*)(ref_w);
    const float4* w1 = (const float4*)(ref_w + DD);
    const float4* w2 = (const float4*)(ref_w + 2*DD);
    #pragma unroll 4
    for (int k=0;k<DD/4;k++) {
        float4 a = qr[k];
        float4 b0 = w0[k], b1 = w1[k], b2 = w2[k];
        a0 += a.x*b0.x + a.y*b0.y + a.z*b0.z + a.w*b0.w;
        a1 += a.x*b1.x + a.y*b1.y + a.z*b1.z + a.w*b1.w;
        a2 += a.x*b2.x + a.y*b2.y + a.z*b2.z + a.w*b2.w;
    }
    float h0 = sigmoidf_(a0), h1 = sigmoidf_(a1), h2 = sigmoidf_(a2);
    const float* m = l2i + bn*16;
    float px = m[0]*h0+m[1]*h1+m[2]*h2+m[3];
    float py = m[4]*h0+m[5]*h1+m[6]*h2+m[7];
    float pz = m[8]*h0+m[9]*h1+m[10]*h2+m[11];
    float denom = fabsf(pz)+1e-5f;
    float sx = px/denom, sy = py/denom;
    float pnx = sx/(float)(WW-1)*2.0f-1.0f;
    float pny = sy/(float)(HH-1)*2.0f-1.0f;
    maskz[idx] = (pz > 1e-5f) ? 1 : 0;
    inimg[idx] = (fmaxf(fabsf(pnx),fabsf(pny)) < 1.0f) ? 1 : 0;
    float ix = (pnx+1.0f)*(WW*0.5f)-0.5f;
    float iy = (pny+1.0f)*(HH*0.5f)-0.5f;
    float x0f = floorf(ix), y0f = floorf(iy);
    wxa[idx] = ix-x0f; wya[idx] = iy-y0f;
    x0a[idx] = (int)x0f; y0a[idx] = (int)y0f;
}

// ---------------- bilinear gather + masked mean over cams + add q ----------------
// Phase split: issue ALL (up to 24) scattered loads first (values land in regs,
// no consumer), then one waitcnt + FMA accumulate. Removes the per-camera
// vmcnt round-trip serialization (~900cy cold HBM each). Block-uniform metadata
// staged once through LDS instead of 256x36 redundant global loads.
__global__ __launch_bounds__(256) void sample_kernel(const float* __restrict__ feats,
        const float* __restrict__ qe, const float* __restrict__ wxa, const float* __restrict__ wya,
        const int* __restrict__ x0a, const int* __restrict__ y0a,
        const int* __restrict__ maskz, const int* __restrict__ inimg,
        float* __restrict__ xout) {
    __shared__ float swx[NCAM], swy[NCAM];
    __shared__ int sx0[NCAM], sy0[NCAM], sval[NCAM];
    int bq = blockIdx.x;
    int b = bq / QQ, q = bq % QQ;
    int t = threadIdx.x;
    if (t < NCAM) {
        int n = t;
        int s = (b*NCAM+n)*QQ + q;          // matched (b,n,q) index
        int sq = b*(NCAM*QQ) + q*NCAM + n;  // reference's reshape-scrambled index
        sval[n] = maskz[s] & inimg[sq];
        swx[n] = wxa[s]; swy[n] = wya[s];
        sx0[n] = x0a[s]; sy0[n] = y0a[s];
    }
    __syncthreads();
    int c = t;
    float v00[NCAM] = {}, v10[NCAM] = {}, v01[NCAM] = {}, v11[NCAM] = {};
    float W00[NCAM], W10[NCAM], W01[NCAM], W11[NCAM];
    int cnt = 0;
    // phase 1: weights + load issue (no consumers of loaded values here)
    #pragma unroll
    for (int n = 0; n < NCAM; n++) {
        int valid = sval[n];
        float wx = swx[n], wy = swy[n];
        int x0 = sx0[n], y0 = sy0[n];
        int x1 = x0 + 1, y1 = y0 + 1;
        bool x0in = (unsigned)x0 < (unsigned)WW;
        bool x1in = (unsigned)x1 < (unsigned)WW;
        bool y0in = (unsigned)y0 < (unsigned)HH;
        bool y1in = (unsigned)y1 < (unsigned)HH;
        int x0c = x0in ? x0 : 0;
        int x1c = x1in ? x1 : (WW-1);
        int y0c = y0in ? y0 : 0;
        int y1c = y1in ? y1 : (HH-1);
        W00[n] = (x0in && y0in) ? (1.f-wx)*(1.f-wy) : 0.f;
        W10[n] = (x1in && y0in) ? wx*(1.f-wy) : 0.f;
        W01[n] = (x0in && y1in) ? (1.f-wx)*wy : 0.f;
        W11[n] = (x1in && y1in) ? wx*wy : 0.f;
        cnt += valid;
        if (valid) {
            const float* fb = feats + ((size_t)(b*NCAM+n)*CC + c)*HWSZ;
            const float* r0 = fb + y0c*WW;
            const float* r1 = fb + y1c*WW;
            v00[n] = r0[x0c]; v10[n] = r0[x1c];
            v01[n] = r1[x0c]; v11[n] = r1[x1c];
        }
    }
    // phase 2: single drain + accumulate
    float sum = 0.0f;
    #pragma unroll
    for (int n = 0; n < NCAM; n++)
        sum += W00[n]*v00[n] + W10[n]*v10[n] + W01[n]*v01[n] + W11[n]*v11[n];
    float tgt = sum / (float)(cnt > 0 ? cnt : 1);
    xout[(size_t)bq*DD + c] = qe[q*DD+c] + tgt;
}

// ---------------- tiled SGEMM: C[M,N] = A[M,K] @ Wt[N,K]^T + bias[N] ----------------
// COMB=true fuses the split-K attention combine into A staging:
// A[m][k] = (opA[...]+opB[...]) / (lA[...]+lB[...]), m=(b,q), k=(h,d).
#define TILE 64
#define BKK 16
template<bool COMB>
__global__ __launch_bounds__(256) void sgemm_nt(const float* __restrict__ A,
        const float* __restrict__ A2, const float* __restrict__ lA, const float* __restrict__ lB,
        const float* __restrict__ Bw, const float* __restrict__ bias,
        float* __restrict__ Cm, int M, int N, int K) {
    __shared__ float As[BKK][TILE+4];
    __shared__ float Bs[BKK][TILE+4];
    int tid = threadIdx.x;
    int m0 = blockIdx.y * TILE, n0 = blockIdx.x * TILE;
    float acc[4][4] = {};
    int tx = tid & 15, ty = tid >> 4;
    int ms = tid >> 2;              // staging row 0..63
    int kq = (tid & 3) * 4;         // staging k seg
    for (int k0 = 0; k0 < K; k0 += BKK) {
        int gm = m0 + ms;
        float4 fa = make_float4(0.f,0.f,0.f,0.f);
        if (gm < M) {
            if (COMB) {
                int k = k0 + kq;
                int h = k >> 5, d = k & 31;           // k..k+3 stay in one head (k%4==0)
                int b = (gm >= QQ) ? 1 : 0;
                int qq_ = gm - b*QQ;
                size_t base = ((size_t)(b*NHD+h))*QQ + qq_;
                const float4 o1 = *(const float4*)(A  + base*HD + d);
                const float4 o2 = *(const float4*)(A2 + base*HD + d);
                float L = lA[base] + lB[base];
                float r = 1.0f / L;
                fa = make_float4((o1.x+o2.x)*r, (o1.y+o2.y)*r, (o1.z+o2.z)*r, (o1.w+o2.w)*r);
            } else {
                fa = *(const float4*)(A + (size_t)gm * K + k0 + kq);
            }
        }
        As[kq+0][ms]=fa.x; As[kq+1][ms]=fa.y; As[kq+2][ms]=fa.z; As[kq+3][ms]=fa.w;
        int gn = n0 + ms;
        float4 fb = (gn < N) ? *(const float4*)(Bw + (size_t)gn * K + k0 + kq)
                             : make_float4(0.f,0.f,0.f,0.f);
        Bs[kq+0][ms]=fb.x; Bs[kq+1][ms]=fb.y; Bs[kq+2][ms]=fb.z; Bs[kq+3][ms]=fb.w;
        __syncthreads();
        #pragma unroll
        for (int k = 0; k < BKK; k++) {
            float a[4], bb[4];
            #pragma unroll
            for (int i = 0; i < 4; i++) a[i] = As[k][ty*4+i];
            #pragma unroll
            for (int j = 0; j < 4; j++) bb[j] = Bs[k][tx*4+j];
            #pragma unroll
            for (int i = 0; i < 4; i++)
                #pragma unroll
                for (int j = 0; j < 4; j++)
                    acc[i][j] += a[i] * bb[j];
        }
        __syncthreads();
    }
    for (int i = 0; i < 4; i++) {
        int gm = m0 + ty*4 + i;
        if (gm >= M) continue;
        for (int j = 0; j < 4; j++) {
            int gn = n0 + tx*4 + j;
            if (gn < N) Cm[(size_t)gm * N + gn] = acc[i][j] + bias[gn];
        }
    }
}

// ---------------- flash-style attention, split-K x2 ----------------
// No max-subtraction (scores O(1); softmax shift-invariant); split-K partials
// combine exactly as (O0+O1)/(l0+l1) - done inside the out-proj GEMM staging.
#define QTILE 32
#define KTILE 64
#define NQB 29
__global__ __launch_bounds__(256) void attn_flash(const float* __restrict__ qkv,
        float* __restrict__ opA, float* __restrict__ opB,
        float* __restrict__ lpA, float* __restrict__ lpB) {
    __shared__ __align__(16) float Ks[32][68];   // [d][k]
    __shared__ __align__(16) float Vs[64][36];   // [k][d]
    __shared__ __align__(16) float Ps[32][68];   // [q][k]; also Q staging [d][q]
    int blk = blockIdx.x;
    int qb = blk % NQB;
    int h  = (blk / NQB) % NHD;
    int b  = (blk / (NQB*NHD)) % BB;
    int ks = blk / (NQB*NHD*BB);
    int q0 = qb * QTILE;
    int tid = threadIdx.x;
    int tx = tid & 15, ty = tid >> 4;

    // stage Q tile transposed into Ps area: Ps[d][q]
    {
        int q = tid >> 3;            // 0..31
        int dseg = (tid & 7) * 4;
        int gq = q0 + q; if (gq > QQ-1) gq = QQ-1;
        const float4 f = *(const float4*)(qkv + ((size_t)(b*QQ+gq))*768 + h*HD + dseg);
        Ps[dseg+0][q] = f.x; Ps[dseg+1][q] = f.y; Ps[dseg+2][q] = f.z; Ps[dseg+3][q] = f.w;
    }
    __syncthreads();
    float q0r[32], q1r[32];
    #pragma unroll
    for (int d = 0; d < 32; d++) { q0r[d] = Ps[d][ty*2]; q1r[d] = Ps[d][ty*2+1]; }
    __syncthreads();

    float O[2][2] = {};
    float l[2] = {0.f, 0.f};
    const float scale = 0.17677669529663689f; // 1/sqrt(32)
    int kt0 = ks ? 8 : 0;
    int kt1 = ks ? 15 : 8;

    for (int kt = kt0; kt < kt1; kt++) {
        int k0 = kt * KTILE;
        // stage K (transposed) and V tiles
        {
            int k = tid >> 2;            // 0..63
            int dseg = (tid & 3) * 8;
            int gk = k0 + k; if (gk > QQ-1) gk = QQ-1;
            const float* kp = qkv + ((size_t)(b*QQ+gk))*768 + 256 + h*HD + dseg;
            float4 f0 = *(const float4*)(kp);
            float4 f1 = *(const float4*)(kp+4);
            Ks[dseg+0][k]=f0.x; Ks[dseg+1][k]=f0.y; Ks[dseg+2][k]=f0.z; Ks[dseg+3][k]=f0.w;
            Ks[dseg+4][k]=f1.x; Ks[dseg+5][k]=f1.y; Ks[dseg+6][k]=f1.z; Ks[dseg+7][k]=f1.w;
            const float* vp = qkv + ((size_t)(b*QQ+gk))*768 + 512 + h*HD + dseg;
            *(float4*)(&Vs[k][dseg])   = *(const float4*)(vp);
            *(float4*)(&Vs[k][dseg+4]) = *(const float4*)(vp+4);
        }
        __syncthreads();

        // scores: 2q x 4k register fragment; Q from registers, only K from LDS
        float acc[2][4] = {};
        #pragma unroll
        for (int d = 0; d < 32; d++) {
            float4 bk = *(const float4*)(&Ks[d][tx*4]);
            float a0 = q0r[d], a1 = q1r[d];
            acc[0][0] += a0*bk.x; acc[0][1] += a0*bk.y; acc[0][2] += a0*bk.z; acc[0][3] += a0*bk.w;
            acc[1][0] += a1*bk.x; acc[1][1] += a1*bk.y; acc[1][2] += a1*bk.z; acc[1][3] += a1*bk.w;
        }
        // exp + tail mask + row-sum across tx
        #pragma unroll
        for (int i = 0; i < 2; i++) {
            float e[4];
            float rs = 0.f;
            #pragma unroll
            for (int j = 0; j < 4; j++) {
                int gk = k0 + tx*4 + j;
                float v = (gk < QQ) ? __expf(acc[i][j]*scale) : 0.f;
                e[j] = v; rs += v;
            }
            #pragma unroll
            for (int m = 1; m < 16; m <<= 1) rs += __shfl_xor(rs, m, 16);
            l[i] += rs;
            *(float4*)(&Ps[ty*2+i][tx*4]) = make_float4(e[0],e[1],e[2],e[3]);
        }
        __syncthreads();

        // PV: O[2q][2d] accumulate
        #pragma unroll
        for (int k4 = 0; k4 < 16; k4++) {
            float4 p0 = *(const float4*)(&Ps[ty*2][k4*4]);
            float4 p1 = *(const float4*)(&Ps[ty*2+1][k4*4]);
            float2 v0 = *(const float2*)(&Vs[k4*4+0][tx*2]);
            float2 v1 = *(const float2*)(&Vs[k4*4+1][tx*2]);
            float2 v2 = *(const float2*)(&Vs[k4*4+2][tx*2]);
            float2 v3 = *(const float2*)(&Vs[k4*4+3][tx*2]);
            O[0][0] += p0.x*v0.x + p0.y*v1.x + p0.z*v2.x + p0.w*v3.x;
            O[0][1] += p0.x*v0.y + p0.y*v1.y + p0.z*v2.y + p0.w*v3.y;
            O[1][0] += p1.x*v0.x + p1.y*v1.x + p1.z*v2.x + p1.w*v3.x;
            O[1][1] += p1.x*v0.y + p1.y*v1.y + p1.z*v2.y + p1.w*v3.y;
        }
        __syncthreads();
    }

    float* op = ks ? opB : opA;
    float* lp = ks ? lpB : lpA;
    #pragma unroll
    for (int i = 0; i < 2; i++) {
        int gq = q0 + ty*2 + i;
        if (gq < QQ) {
            float* o = op + (((size_t)(b*NHD+h))*QQ + gq)*HD + tx*2;
            o[0] = O[i][0];
            o[1] = O[i][1];
            if (tx == 0) lp[(b*NHD+h)*QQ + gq] = l[i];
        }
    }
}

// ---------------- layernorm + cls/box heads ----------------
__global__ __launch_bounds__(256) void final_kernel(const float* __restrict__ o,
    const float* __restrict__ norm_w, const float* __restrict__ norm_b,
    const float* __restrict__ cls_w, const float* __restrict__ cls_b,
    const float* __restrict__ box_w, const float* __restrict__ box_b,
    float* __restrict__ out) {
    __shared__ float s_xn[DD];
    __shared__ float red[8];
    int bq = blockIdx.x;
    int t = threadIdx.x;
    float val = o[(size_t)bq*DD + t];
    float v1 = val, v2 = val*val;
    for (int off=32; off>0; off>>=1) { v1 += __shfl_down(v1, off); v2 += __shfl_down(v2, off); }
    if ((t & 63) == 0) { red[t>>6] = v1; red[4 + (t>>6)] = v2; }
    __syncthreads();
    float ssum = red[0]+red[1]+red[2]+red[3];
    float ssq  = red[4]+red[5]+red[6]+red[7];
    float mu = ssum / (float)DD;
    float var = ssq / (float)DD - mu*mu;
    float inv = 1.0f / sqrtf(var + 1e-5f);
    s_xn[t] = (val - mu)*inv*norm_w[t] + norm_b[t];
    __syncthreads();
    int j = t >> 5, lane = t & 31;
    const float* wrow = (j < 2) ? (cls_w + j*DD) : (box_w + (j-2)*DD);
    float acc = 0.f;
    for (int k=lane; k<DD; k+=32) acc += s_xn[k]*wrow[k];
    for (int off=16; off>0; off>>=1) acc += __shfl_down(acc, off, 32);
    if (lane == 0) {
        if (j < 2) {
            out[(size_t)bq*2 + j] = acc + cls_b[j];
        } else {
            int jj = j-2;
            float v = acc + box_b[jj];
            if (jj < 3) v = sigmoidf_(v);
            out[BB*QQ*2 + (size_t)bq*6 + jj] = v;
        }
    }
}

extern "C" void kernel_launch(void* const* d_in, const int* in_sizes, int n_in,
                              void* d_out, int out_size, void* d_ws, size_t ws_size,
                              hipStream_t stream) {
    const float* feats = (const float*)d_in[0];
    const float* l2i   = (const float*)d_in[1];
    const float* qe    = (const float*)d_in[2];
    const float* ref_w = (const float*)d_in[3];
    const float* ref_b = (const float*)d_in[4];
    const float* ipw   = (const float*)d_in[5];
    const float* ipb   = (const float*)d_in[6];
    const float* opw   = (const float*)d_in[7];
    const float* opb   = (const float*)d_in[8];
    const float* nw    = (const float*)d_in[9];
    const float* nb    = (const float*)d_in[10];
    const float* clsw  = (const float*)d_in[11];
    const float* clsb  = (const float*)d_in[12];
    const float* boxw  = (const float*)d_in[13];
    const float* boxb  = (const float*)d_in[14];
    float* out = (float*)d_out;
    float* ws = (float*)d_ws;

    float* ref   = ws;                         // 2700 (unused now, layout kept)
    float* wxa   = ws + 2700;                  // 10800
    float* wya   = wxa + 10800;                // 10800
    int*   x0a   = (int*)(wya + 10800);        // 10800
    int*   y0a   = x0a + 10800;                // 10800
    int*   maskz = y0a + 10800;                // 10800
    int*   inimg = maskz + 10800;              // 10800
    float* x     = (float*)(inimg + 10800);    // 1800*256
    float* qkv   = x + 460800;                 // 1800*768
    float* attn  = qkv + 1382400;              // 1800*256 (now: opB partial)
    float* oproj = attn + 460800;              // 1800*256
    (void)ref;

    // split-K attention partial overlays (all regions dead during attn phase):
    float* opA = x;            // x dead after qkv GEMM; 460800 = 2*8*900*32 exactly
    float* opB = attn;         // attn buffer only ever holds the partial now
    float* lpA = wxa;          // proj scratch dead after sample_kernel (needs 14400)
    float* lpB = wxa + 14400;  // next 14400, still within proj scratch

    proj_kernel<<<(BB*NCAM*QQ+255)/256, 256, 0, stream>>>(l2i, qe, ref_w, ref_b,
                                                          wxa, wya, x0a, y0a, maskz, inimg);
    sample_kernel<<<BB*QQ, 256, 0, stream>>>(feats, qe, wxa, wya, x0a, y0a, maskz, inimg, x);
    sgemm_nt<false><<<dim3(768/TILE, (BB*QQ+TILE-1)/TILE), 256, 0, stream>>>(
        x, nullptr, nullptr, nullptr, ipw, ipb, qkv, BB*QQ, 768, 256);
    attn_flash<<<BB*NHD*NQB*2, 256, 0, stream>>>(qkv, opA, opB, lpA, lpB);
    sgemm_nt<true><<<dim3(256/TILE, (BB*QQ+TILE-1)/TILE), 256, 0, stream>>>(
        opA, opB, lpA, lpB, opw, opb, oproj, BB*QQ, 256, 256);
    final_kernel<<<BB*QQ, 256, 0, stream>>>(oproj, nw, nb, clsw, clsb, boxw, boxb, out);
}

// Round 3
// 461.989 us; speedup vs baseline: 1.0930x; 1.0090x over previous
//
#include <hip/hip_runtime.h>
#include <math.h>

#define BB 2
#define NCAM 6
#define CC 256
#define HH 116
#define WW 200
#define QQ 900
#define DD 256
#define NHD 8
#define HD 32
#define HWSZ (HH*WW)

__device__ __forceinline__ float sigmoidf_(float x){ return 1.0f/(1.0f+expf(-x)); }

// ---------------- fused: ref = sigmoid(q @ ref_w.T + b) + project to cameras ----------------
__global__ void proj_kernel(const float* __restrict__ l2i, const float* __restrict__ qe,
        const float* __restrict__ ref_w, const float* __restrict__ ref_b,
        float* __restrict__ wxa, float* __restrict__ wya,
        int* __restrict__ x0a, int* __restrict__ y0a,
        int* __restrict__ maskz, int* __restrict__ inimg) {
    int idx = blockIdx.x*256+threadIdx.x;
    if (idx >= BB*NCAM*QQ) return;
    int q = idx % QQ;
    int bn = idx / QQ;   // b*NCAM+n
    float a0 = ref_b[0], a1 = ref_b[1], a2 = ref_b[2];
    const float4* qr = (const float4*)(qe + (size_t)q*DD);
    const float4* w0 = (const float4*)(ref_w);
    const float4* w1 = (const float4*)(ref_w + DD);
    const float4* w2 = (const float4*)(ref_w + 2*DD);
    #pragma unroll 4
    for (int k=0;k<DD/4;k++) {
        float4 a = qr[k];
        float4 b0 = w0[k], b1 = w1[k], b2 = w2[k];
        a0 += a.x*b0.x + a.y*b0.y + a.z*b0.z + a.w*b0.w;
        a1 += a.x*b1.x + a.y*b1.y + a.z*b1.z + a.w*b1.w;
        a2 += a.x*b2.x + a.y*b2.y + a.z*b2.z + a.w*b2.w;
    }
    float h0 = sigmoidf_(a0), h1 = sigmoidf_(a1), h2 = sigmoidf_(a2);
    const float* m = l2i + bn*16;
    float px = m[0]*h0+m[1]*h1+m[2]*h2+m[3];
    float py = m[4]*h0+m[5]*h1+m[6]*h2+m[7];
    float pz = m[8]*h0+m[9]*h1+m[10]*h2+m[11];
    float denom = fabsf(pz)+1e-5f;
    float sx = px/denom, sy = py/denom;
    float pnx = sx/(float)(WW-1)*2.0f-1.0f;
    float pny = sy/(float)(HH-1)*2.0f-1.0f;
    maskz[idx] = (pz > 1e-5f) ? 1 : 0;
    inimg[idx] = (fmaxf(fabsf(pnx),fabsf(pny)) < 1.0f) ? 1 : 0;
    float ix = (pnx+1.0f)*(WW*0.5f)-0.5f;
    float iy = (pny+1.0f)*(HH*0.5f)-0.5f;
    float x0f = floorf(ix), y0f = floorf(iy);
    wxa[idx] = ix-x0f; wya[idx] = iy-y0f;
    x0a[idx] = (int)x0f; y0a[idx] = (int)y0f;
}

// ---------------- bilinear gather + masked mean over cams + add q ----------------
__global__ __launch_bounds__(256) void sample_kernel(const float* __restrict__ feats,
        const float* __restrict__ qe, const float* __restrict__ wxa, const float* __restrict__ wya,
        const int* __restrict__ x0a, const int* __restrict__ y0a,
        const int* __restrict__ maskz, const int* __restrict__ inimg,
        float* __restrict__ xout) {
    __shared__ float swx[NCAM], swy[NCAM];
    __shared__ int sx0[NCAM], sy0[NCAM], sval[NCAM];
    int bq = blockIdx.x;
    int b = bq / QQ, q = bq % QQ;
    int t = threadIdx.x;
    if (t < NCAM) {
        int n = t;
        int s = (b*NCAM+n)*QQ + q;          // matched (b,n,q) index
        int sq = b*(NCAM*QQ) + q*NCAM + n;  // reference's reshape-scrambled index
        sval[n] = maskz[s] & inimg[sq];
        swx[n] = wxa[s]; swy[n] = wya[s];
        sx0[n] = x0a[s]; sy0[n] = y0a[s];
    }
    __syncthreads();
    int c = t;
    float v00[NCAM] = {}, v10[NCAM] = {}, v01[NCAM] = {}, v11[NCAM] = {};
    float W00[NCAM], W10[NCAM], W01[NCAM], W11[NCAM];
    int cnt = 0;
    #pragma unroll
    for (int n = 0; n < NCAM; n++) {
        int valid = sval[n];
        float wx = swx[n], wy = swy[n];
        int x0 = sx0[n], y0 = sy0[n];
        int x1 = x0 + 1, y1 = y0 + 1;
        bool x0in = (unsigned)x0 < (unsigned)WW;
        bool x1in = (unsigned)x1 < (unsigned)WW;
        bool y0in = (unsigned)y0 < (unsigned)HH;
        bool y1in = (unsigned)y1 < (unsigned)HH;
        int x0c = x0in ? x0 : 0;
        int x1c = x1in ? x1 : (WW-1);
        int y0c = y0in ? y0 : 0;
        int y1c = y1in ? y1 : (HH-1);
        W00[n] = (x0in && y0in) ? (1.f-wx)*(1.f-wy) : 0.f;
        W10[n] = (x1in && y0in) ? wx*(1.f-wy) : 0.f;
        W01[n] = (x0in && y1in) ? (1.f-wx)*wy : 0.f;
        W11[n] = (x1in && y1in) ? wx*wy : 0.f;
        cnt += valid;
        if (valid) {
            const float* fb = feats + ((size_t)(b*NCAM+n)*CC + c)*HWSZ;
            const float* r0 = fb + y0c*WW;
            const float* r1 = fb + y1c*WW;
            v00[n] = r0[x0c]; v10[n] = r0[x1c];
            v01[n] = r1[x0c]; v11[n] = r1[x1c];
        }
    }
    float sum = 0.0f;
    #pragma unroll
    for (int n = 0; n < NCAM; n++)
        sum += W00[n]*v00[n] + W10[n]*v10[n] + W01[n]*v01[n] + W11[n]*v11[n];
    float tgt = sum / (float)(cnt > 0 ? cnt : 1);
    xout[(size_t)bq*DD + c] = qe[q*DD+c] + tgt;
}

// ---------------- tiled SGEMM: C[M,N] = A[M,K] @ Wt[N,K]^T + bias[N] ----------------
#define TILE 64
#define BKK 16
__global__ __launch_bounds__(256) void sgemm_nt(const float* __restrict__ A,
        const float* __restrict__ Bw, const float* __restrict__ bias,
        float* __restrict__ Cm, int M, int N, int K) {
    __shared__ float As[BKK][TILE+4];
    __shared__ float Bs[BKK][TILE+4];
    int tid = threadIdx.x;
    int m0 = blockIdx.y * TILE, n0 = blockIdx.x * TILE;
    float acc[4][4] = {};
    int tx = tid & 15, ty = tid >> 4;
    int ms = tid >> 2;              // staging row 0..63
    int kq = (tid & 3) * 4;         // staging k seg
    for (int k0 = 0; k0 < K; k0 += BKK) {
        int gm = m0 + ms;
        float4 fa = (gm < M) ? *(const float4*)(A + (size_t)gm * K + k0 + kq)
                             : make_float4(0.f,0.f,0.f,0.f);
        As[kq+0][ms]=fa.x; As[kq+1][ms]=fa.y; As[kq+2][ms]=fa.z; As[kq+3][ms]=fa.w;
        int gn = n0 + ms;
        float4 fb = (gn < N) ? *(const float4*)(Bw + (size_t)gn * K + k0 + kq)
                             : make_float4(0.f,0.f,0.f,0.f);
        Bs[kq+0][ms]=fb.x; Bs[kq+1][ms]=fb.y; Bs[kq+2][ms]=fb.z; Bs[kq+3][ms]=fb.w;
        __syncthreads();
        #pragma unroll
        for (int k = 0; k < BKK; k++) {
            float a[4], bb[4];
            #pragma unroll
            for (int i = 0; i < 4; i++) a[i] = As[k][ty*4+i];
            #pragma unroll
            for (int j = 0; j < 4; j++) bb[j] = Bs[k][tx*4+j];
            #pragma unroll
            for (int i = 0; i < 4; i++)
                #pragma unroll
                for (int j = 0; j < 4; j++)
                    acc[i][j] += a[i] * bb[j];
        }
        __syncthreads();
    }
    for (int i = 0; i < 4; i++) {
        int gm = m0 + ty*4 + i;
        if (gm >= M) continue;
        for (int j = 0; j < 4; j++) {
            int gn = n0 + tx*4 + j;
            if (gn < N) Cm[(size_t)gm * N + gn] = acc[i][j] + bias[gn];
        }
    }
}

// ---------------- flash-style attention, split-K x2 ----------------
#define QTILE 32
#define KTILE 64
#define NQB 29
__global__ __launch_bounds__(256) void attn_flash(const float* __restrict__ qkv,
        float* __restrict__ opA, float* __restrict__ opB,
        float* __restrict__ lpA, float* __restrict__ lpB) {
    __shared__ __align__(16) float Ks[32][68];   // [d][k]
    __shared__ __align__(16) float Vs[64][36];   // [k][d]
    __shared__ __align__(16) float Ps[32][68];   // [q][k]; also Q staging [d][q]
    int blk = blockIdx.x;
    int qb = blk % NQB;
    int h  = (blk / NQB) % NHD;
    int b  = (blk / (NQB*NHD)) % BB;
    int ks = blk / (NQB*NHD*BB);
    int q0 = qb * QTILE;
    int tid = threadIdx.x;
    int tx = tid & 15, ty = tid >> 4;

    {
        int q = tid >> 3;            // 0..31
        int dseg = (tid & 7) * 4;
        int gq = q0 + q; if (gq > QQ-1) gq = QQ-1;
        const float4 f = *(const float4*)(qkv + ((size_t)(b*QQ+gq))*768 + h*HD + dseg);
        Ps[dseg+0][q] = f.x; Ps[dseg+1][q] = f.y; Ps[dseg+2][q] = f.z; Ps[dseg+3][q] = f.w;
    }
    __syncthreads();
    float q0r[32], q1r[32];
    #pragma unroll
    for (int d = 0; d < 32; d++) { q0r[d] = Ps[d][ty*2]; q1r[d] = Ps[d][ty*2+1]; }
    __syncthreads();

    float O[2][2] = {};
    float l[2] = {0.f, 0.f};
    const float scale = 0.17677669529663689f; // 1/sqrt(32)
    int kt0 = ks ? 8 : 0;
    int kt1 = ks ? 15 : 8;

    for (int kt = kt0; kt < kt1; kt++) {
        int k0 = kt * KTILE;
        {
            int k = tid >> 2;            // 0..63
            int dseg = (tid & 3) * 8;
            int gk = k0 + k; if (gk > QQ-1) gk = QQ-1;
            const float* kp = qkv + ((size_t)(b*QQ+gk))*768 + 256 + h*HD + dseg;
            float4 f0 = *(const float4*)(kp);
            float4 f1 = *(const float4*)(kp+4);
            Ks[dseg+0][k]=f0.x; Ks[dseg+1][k]=f0.y; Ks[dseg+2][k]=f0.z; Ks[dseg+3][k]=f0.w;
            Ks[dseg+4][k]=f1.x; Ks[dseg+5][k]=f1.y; Ks[dseg+6][k]=f1.z; Ks[dseg+7][k]=f1.w;
            const float* vp = qkv + ((size_t)(b*QQ+gk))*768 + 512 + h*HD + dseg;
            *(float4*)(&Vs[k][dseg])   = *(const float4*)(vp);
            *(float4*)(&Vs[k][dseg+4]) = *(const float4*)(vp+4);
        }
        __syncthreads();

        float acc[2][4] = {};
        #pragma unroll
        for (int d = 0; d < 32; d++) {
            float4 bk = *(const float4*)(&Ks[d][tx*4]);
            float a0 = q0r[d], a1 = q1r[d];
            acc[0][0] += a0*bk.x; acc[0][1] += a0*bk.y; acc[0][2] += a0*bk.z; acc[0][3] += a0*bk.w;
            acc[1][0] += a1*bk.x; acc[1][1] += a1*bk.y; acc[1][2] += a1*bk.z; acc[1][3] += a1*bk.w;
        }
        #pragma unroll
        for (int i = 0; i < 2; i++) {
            float e[4];
            float rs = 0.f;
            #pragma unroll
            for (int j = 0; j < 4; j++) {
                int gk = k0 + tx*4 + j;
                float v = (gk < QQ) ? __expf(acc[i][j]*scale) : 0.f;
                e[j] = v; rs += v;
            }
            #pragma unroll
            for (int m = 1; m < 16; m <<= 1) rs += __shfl_xor(rs, m, 16);
            l[i] += rs;
            *(float4*)(&Ps[ty*2+i][tx*4]) = make_float4(e[0],e[1],e[2],e[3]);
        }
        __syncthreads();

        #pragma unroll
        for (int k4 = 0; k4 < 16; k4++) {
            float4 p0 = *(const float4*)(&Ps[ty*2][k4*4]);
            float4 p1 = *(const float4*)(&Ps[ty*2+1][k4*4]);
            float2 v0 = *(const float2*)(&Vs[k4*4+0][tx*2]);
            float2 v1 = *(const float2*)(&Vs[k4*4+1][tx*2]);
            float2 v2 = *(const float2*)(&Vs[k4*4+2][tx*2]);
            float2 v3 = *(const float2*)(&Vs[k4*4+3][tx*2]);
            O[0][0] += p0.x*v0.x + p0.y*v1.x + p0.z*v2.x + p0.w*v3.x;
            O[0][1] += p0.x*v0.y + p0.y*v1.y + p0.z*v2.y + p0.w*v3.y;
            O[1][0] += p1.x*v0.x + p1.y*v1.x + p1.z*v2.x + p1.w*v3.x;
            O[1][1] += p1.x*v0.y + p1.y*v1.y + p1.z*v2.y + p1.w*v3.y;
        }
        __syncthreads();
    }

    float* op = ks ? opB : opA;
    float* lp = ks ? lpB : lpA;
    #pragma unroll
    for (int i = 0; i < 2; i++) {
        int gq = q0 + ty*2 + i;
        if (gq < QQ) {
            float* o = op + (((size_t)(b*NHD+h))*QQ + gq)*HD + tx*2;
            o[0] = O[i][0];
            o[1] = O[i][1];
            if (tx == 0) lp[(b*NHD+h)*QQ + gq] = l[i];
        }
    }
}

// ---------------- fused tail: split-K combine + out-proj GEMM + LN + cls/box heads ----------------
// 8 full 256-wide rows per block (grid 225). A (attn rows) staged ONCE to LDS with the
// (O0+O1)/(l0+l1) combine applied. B (opw) staged per 16-k tile, transposed so inner
// reads are conflict-free. LN + head dots done per-row by 32-lane groups (wave-internal,
// no extra barriers).
#define TM 8
__global__ __launch_bounds__(256) void tail_kernel(
    const float* __restrict__ opA, const float* __restrict__ opB,
    const float* __restrict__ lpA, const float* __restrict__ lpB,
    const float* __restrict__ opw, const float* __restrict__ opb,
    const float* __restrict__ norm_w, const float* __restrict__ norm_b,
    const float* __restrict__ cls_w, const float* __restrict__ cls_b,
    const float* __restrict__ box_w, const float* __restrict__ box_b,
    float* __restrict__ out) {
    __shared__ __align__(16) float As[TM][264];   // A rows; reused as xn after GEMM
    __shared__ __align__(16) float Bs[BKK][260];
    int t = threadIdx.x;
    int m0 = blockIdx.x * TM;

    // stage A: thread (r, seg) loads 8 combined values at k = seg*8 (one head: d = (seg&3)*8)
    {
        int r = t >> 5, seg = t & 31;
        int gm = m0 + r;
        int b = (gm >= QQ) ? 1 : 0;
        int qq_ = gm - b*QQ;
        int h = seg >> 2, d = (seg & 3) * 8;
        size_t base = ((size_t)(b*NHD+h))*QQ + qq_;
        float4 a0 = *(const float4*)(opA + base*HD + d);
        float4 a1 = *(const float4*)(opA + base*HD + d + 4);
        float4 b0 = *(const float4*)(opB + base*HD + d);
        float4 b1 = *(const float4*)(opB + base*HD + d + 4);
        float rcpL = 1.0f / (lpA[base] + lpB[base]);
        int k = seg * 8;
        *(float4*)(&As[r][k])   = make_float4((a0.x+b0.x)*rcpL,(a0.y+b0.y)*rcpL,(a0.z+b0.z)*rcpL,(a0.w+b0.w)*rcpL);
        *(float4*)(&As[r][k+4]) = make_float4((a1.x+b1.x)*rcpL,(a1.y+b1.y)*rcpL,(a1.z+b1.z)*rcpL,(a1.w+b1.w)*rcpL);
    }

    float acc[TM] = {};
    int nn = t >> 2, sg = t & 3;
    for (int k0 = 0; k0 < DD; k0 += BKK) {
        // stage Bs[k][n] = opw[n][k], transposed, conflict-free on read
        #pragma unroll
        for (int ii = 0; ii < 4; ii++) {
            int n = nn + ii*64;
            float4 f = *(const float4*)(opw + (size_t)n*DD + k0 + sg*4);
            Bs[sg*4+0][n]=f.x; Bs[sg*4+1][n]=f.y; Bs[sg*4+2][n]=f.z; Bs[sg*4+3][n]=f.w;
        }
        __syncthreads();
        #pragma unroll
        for (int kk = 0; kk < 4; kk++) {
            float b0 = Bs[kk*4+0][t], b1 = Bs[kk*4+1][t], b2 = Bs[kk*4+2][t], b3 = Bs[kk*4+3][t];
            #pragma unroll
            for (int r = 0; r < TM; r++) {
                float4 a = *(const float4*)(&As[r][k0 + kk*4]);
                acc[r] += a.x*b0 + a.y*b1 + a.z*b2 + a.w*b3;
            }
        }
        __syncthreads();
    }

    // write raw o rows (bias added); As region reused as o/xn storage
    float bn_ = opb[t];
    #pragma unroll
    for (int r = 0; r < TM; r++) As[r][t] = acc[r] + bn_;
    __syncthreads();

    // per-row LN + heads: row r handled by its own 32-lane group (r = t>>5)
    {
        int r = t >> 5, lane = t & 31;
        int gm = m0 + r;
        float s1 = 0.f, s2 = 0.f;
        #pragma unroll
        for (int i = 0; i < 8; i++) {
            float v = As[r][lane + i*32];
            s1 += v; s2 += v*v;
        }
        #pragma unroll
        for (int off = 16; off > 0; off >>= 1) {
            s1 += __shfl_down(s1, off, 32);
            s2 += __shfl_down(s2, off, 32);
        }
        s1 = __shfl(s1, 0, 32);
        s2 = __shfl(s2, 0, 32);
        float mu = s1 / (float)DD;
        float var = s2 / (float)DD - mu*mu;
        float inv = 1.0f / sqrtf(var + 1e-5f);
        // normalize in place (same 32-lane group writes & reads its own row)
        #pragma unroll
        for (int i = 0; i < 8; i++) {
            int k = lane + i*32;
            As[r][k] = (As[r][k] - mu)*inv*norm_w[k] + norm_b[k];
        }
        // 8 outputs per row: subgroup j = lane>>2 (4 lanes each)
        int j = lane >> 2, kb = lane & 3;
        const float* wrow = (j < 2) ? (cls_w + j*DD) : (box_w + (j-2)*DD);
        float accd = 0.f;
        #pragma unroll 16
        for (int i = 0; i < 64; i++) {
            int k = kb + i*4;
            accd += As[r][k] * wrow[k];
        }
        accd += __shfl_xor(accd, 1, 4);
        accd += __shfl_xor(accd, 2, 4);
        if (kb == 0) {
            if (j < 2) {
                out[(size_t)gm*2 + j] = accd + cls_b[j];
            } else {
                int jj = j - 2;
                float v = accd + box_b[jj];
                if (jj < 3) v = sigmoidf_(v);
                out[BB*QQ*2 + (size_t)gm*6 + jj] = v;
            }
        }
    }
}

extern "C" void kernel_launch(void* const* d_in, const int* in_sizes, int n_in,
                              void* d_out, int out_size, void* d_ws, size_t ws_size,
                              hipStream_t stream) {
    const float* feats = (const float*)d_in[0];
    const float* l2i   = (const float*)d_in[1];
    const float* qe    = (const float*)d_in[2];
    const float* ref_w = (const float*)d_in[3];
    const float* ref_b = (const float*)d_in[4];
    const float* ipw   = (const float*)d_in[5];
    const float* ipb   = (const float*)d_in[6];
    const float* opw   = (const float*)d_in[7];
    const float* opb   = (const float*)d_in[8];
    const float* nw    = (const float*)d_in[9];
    const float* nb    = (const float*)d_in[10];
    const float* clsw  = (const float*)d_in[11];
    const float* clsb  = (const float*)d_in[12];
    const float* boxw  = (const float*)d_in[13];
    const float* boxb  = (const float*)d_in[14];
    float* out = (float*)d_out;
    float* ws = (float*)d_ws;

    float* wxa   = ws + 2700;                  // 10800
    float* wya   = wxa + 10800;                // 10800
    int*   x0a   = (int*)(wya + 10800);        // 10800
    int*   y0a   = x0a + 10800;                // 10800
    int*   maskz = y0a + 10800;                // 10800
    int*   inimg = maskz + 10800;              // 10800
    float* x     = (float*)(inimg + 10800);    // 1800*256
    float* qkv   = x + 460800;                 // 1800*768
    float* attn  = qkv + 1382400;              // 1800*256 (holds opB partial)

    // split-K attention partial overlays (all regions dead during attn phase):
    float* opA = x;            // x dead after qkv GEMM; 460800 = 2*8*900*32 exactly
    float* opB = attn;
    float* lpA = wxa;          // proj scratch dead after sample_kernel (needs 14400)
    float* lpB = wxa + 14400;

    proj_kernel<<<(BB*NCAM*QQ+255)/256, 256, 0, stream>>>(l2i, qe, ref_w, ref_b,
                                                          wxa, wya, x0a, y0a, maskz, inimg);
    sample_kernel<<<BB*QQ, 256, 0, stream>>>(feats, qe, wxa, wya, x0a, y0a, maskz, inimg, x);
    sgemm_nt<<<dim3(768/TILE, (BB*QQ+TILE-1)/TILE), 256, 0, stream>>>(
        x, ipw, ipb, qkv, BB*QQ, 768, 256);
    attn_flash<<<BB*NHD*NQB*2, 256, 0, stream>>>(qkv, opA, opB, lpA, lpB);
    tail_kernel<<<(BB*QQ)/TM, 256, 0, stream>>>(opA, opB, lpA, lpB, opw, opb,
                                                nw, nb, clsw, clsb, boxw, boxb, out);
}